// Round 3
// baseline (141.240 us; speedup 1.0000x reference)
//
#include <hip/hip_runtime.h>

// Problem constants (fixed by the reference setup)
#define P_ 4
#define B_ 8
#define NPIX 65536              // H*W
#define G_ 4
#define C_ 12
#define NBLK1 1024              // stage-1 blocks
#define CHUNKS (NBLK1 / B_)     // 128 chunks per batch
#define TILE (NPIX / CHUNKS)    // 512 pixels per block
#define ROUNDS (TILE / 64)      // 8 rounds per wave (each wave scans whole tile)
#define NSLOT (C_ * B_ * 21)    // 2016 global sum-slots
// ws layout: partials[slot][CHUNKS], slot = (c*B_ + b)*21 + i
// i: 0..15 = W[a][g], 16..19 = Z[a], 20 = count

__global__ __launch_bounds__(256) void kld_stage1(
    const float* __restrict__ act,     // [P, B, N, G]
    const int*   __restrict__ labels,  // [B, N]
    const float* __restrict__ gci,     // [P*G, C]
    float*       __restrict__ partials)
{
    const int b     = blockIdx.x / CHUNKS;
    const int chunk = blockIdx.x % CHUNKS;
    const int w     = threadIdx.x >> 6;   // wave id 0..3
    const int lane  = threadIdx.x & 63;
    const int cls[3] = { w, w + 4, w + 8 };   // this wave's classes

    // proj_idx for my 3 classes: argmax over 16 rows of gci[:,c] (first max), /G
    int pj[3];
    #pragma unroll
    for (int k = 0; k < 3; ++k) {
        int best = 0; float bv = gci[cls[k]];
        #pragma unroll
        for (int r = 1; r < P_ * G_; ++r) {
            const float v = gci[r * C_ + cls[k]];
            if (v > bv) { bv = v; best = r; }
        }
        pj[k] = best >> 2;   // / G_
    }

    const int* __restrict__ lab = labels + (size_t)b * NPIX + chunk * TILE;

    // prefetch this wave's labels for all rounds (independent coalesced loads)
    int lv[ROUNDS];
    #pragma unroll
    for (int r = 0; r < ROUNDS; ++r) lv[r] = lab[r * 64 + lane];

    float acc[3][21];
    #pragma unroll
    for (int k = 0; k < 3; ++k)
        #pragma unroll
        for (int i = 0; i < 21; ++i) acc[k][i] = 0.0f;

    #pragma unroll
    for (int r = 0; r < ROUNDS; ++r) {
        const int n   = chunk * TILE + r * 64 + lane;   // pixel within [b]
        const int l   = lv[r];
        const int cef = ((unsigned)(l - 1) < (unsigned)C_) ? (l - 1) : C_;
        #pragma unroll
        for (int k = 0; k < 3; ++k) {
            if (cef == cls[k]) {   // divergent: ~5/64 lanes; exec-masked gather
                const float4 v = *reinterpret_cast<const float4*>(
                    act + (((size_t)(pj[k] * B_ + b) * NPIX) + (size_t)n) * G_);
                const float vv[4] = { v.x, v.y, v.z, v.w };
                #pragma unroll
                for (int a = 0; a < 4; ++a) {
                    const float e = __expf(vv[a]);
                    acc[k][16 + a] += e;
                    #pragma unroll
                    for (int g = 0; g < 4; ++g)
                        acc[k][a * 4 + g] = fmaf(e, vv[g], acc[k][a * 4 + g]);
                }
                acc[k][20] += 1.0f;
            }
        }
    }

    // 64-lane butterfly: every lane ends with the wave totals
    #pragma unroll
    for (int off = 32; off >= 1; off >>= 1) {
        #pragma unroll
        for (int k = 0; k < 3; ++k)
            #pragma unroll
            for (int i = 0; i < 21; ++i)
                acc[k][i] += __shfl_xor(acc[k][i], off, 64);
    }

    // lane 0 writes 63 partials non-atomically to this block's private column
    if (lane == 0) {
        #pragma unroll
        for (int k = 0; k < 3; ++k)
            #pragma unroll
            for (int i = 0; i < 21; ++i)
                partials[((size_t)(cls[k] * B_ + b) * 21 + i) * CHUNKS + chunk] = acc[k][i];
    }
}

__global__ __launch_bounds__(1024) void kld_finalize(
    const float* __restrict__ partials,  // [NSLOT][CHUNKS]
    const float* __restrict__ proto,     // [120, C]
    float*       __restrict__ out)
{
    __shared__ float s_sum[NSLOT];
    __shared__ float s_ok[C_];
    __shared__ float s_tot[128];
    __shared__ float s_den[128];
    const int t = threadIdx.x;

    if (t < C_) {   // proto_ok[c] = column sum > 0
        float s = 0.0f;
        #pragma unroll
        for (int r = 0; r < 120; ++r) s += proto[r * C_ + t];
        s_ok[t] = s;
    }

    // phase 1: reduce each slot's CHUNKS partials (coalesced float4 per thread)
    for (int s = t; s < NSLOT; s += 1024) {
        const float4* p = reinterpret_cast<const float4*>(partials + (size_t)s * CHUNKS);
        float4 a = p[0];
        #pragma unroll
        for (int q = 1; q < CHUNKS / 4; ++q) {
            const float4 v = p[q];
            a.x += v.x; a.y += v.y; a.z += v.z; a.w += v.w;
        }
        s_sum[s] = (a.x + a.y) + (a.z + a.w);
    }
    __syncthreads();

    // phase 2: one thread per (c,b) pair
    float tot = 0.0f, den = 0.0f;
    if (t < C_ * B_) {
        const int c = t / B_;
        const float* slot = s_sum + t * 21;
        const float cnt = slot[20];
        if (s_ok[c] > 0.0f && cnt >= 2.0f) {
            float S[4][4];
            #pragma unroll
            for (int a = 0; a < 4; ++a) {
                const float zinv = 1.0f / slot[16 + a];
                #pragma unroll
                for (int g = 0; g < 4; ++g)
                    S[a][g] = slot[a * 4 + g] * zinv;
            }
            #pragma unroll
            for (int j = 0; j < 4; ++j)
                #pragma unroll
                for (int k = 0; k < 4; ++k)
                    if (k > j) {
                        const float kld = 0.5f * (S[j][j] + S[k][k] - S[j][k] - S[k][j]);
                        tot += __expf(-kld);
                    }
            den = 6.0f;   // G*(G-1)/2 pairs
        }
    }

    if (t < 128) { s_tot[t] = tot; s_den[t] = den; }
    __syncthreads();
    #pragma unroll
    for (int s = 64; s >= 1; s >>= 1) {
        if (t < s) { s_tot[t] += s_tot[t + s]; s_den[t] += s_den[t + s]; }
        __syncthreads();
    }
    if (t == 0)
        out[0] = (s_den[0] > 0.0f) ? (s_tot[0] / s_den[0]) : 0.0f;
}

extern "C" void kernel_launch(void* const* d_in, const int* in_sizes, int n_in,
                              void* d_out, int out_size, void* d_ws, size_t ws_size,
                              hipStream_t stream) {
    const float* act    = (const float*)d_in[0];  // [P,B,N,G] fp32
    const int*   labels = (const int*)d_in[1];    // [B,H,W] int32
    const float* proto  = (const float*)d_in[2];  // [120, C] fp32
    const float* gci    = (const float*)d_in[3];  // [P*G, C] fp32
    float* out = (float*)d_out;
    float* ws  = (float*)d_ws;   // needs NSLOT*CHUNKS*4 = 1 MiB; every slot written

    kld_stage1<<<NBLK1, 256, 0, stream>>>(act, labels, gci, ws);
    kld_finalize<<<1, 1024, 0, stream>>>(ws, proto, out);
}

// Round 4
// 87.486 us; speedup vs baseline: 1.6144x; 1.6144x over previous
//
#include <hip/hip_runtime.h>

// Problem constants (fixed by the reference setup)
#define P_ 4
#define B_ 8
#define NPIX 65536              // H*W
#define G_ 4
#define C_ 12
#define CHUNKS 64               // chunks per batch
#define NBLK (B_ * CHUNKS)      // 512 stage-1 blocks (2 per CU)
#define TILE (NPIX / CHUNKS)    // 1024 pixels per block
#define ROUNDS (TILE / 64)      // 16 rounds per wave (all 4 waves scan the tile)
#define NSLOT (C_ * B_ * 21)    // 2016 sum-slots
#define RSTRIDE 65              // padded LDS row stride (odd -> conflict-free)
// ws layout: partials[chunk][slot], slot = (c*B_ + b)*21 + i
// i: 0..15 = W[a][g], 16..19 = Z[a], 20 = count

__global__ __launch_bounds__(256, 2) void kld_stage1(
    const float* __restrict__ act,     // [P, B, N, G]
    const int*   __restrict__ labels,  // [B, N]
    const float* __restrict__ gci,     // [P*G, C]
    float*       __restrict__ partials)
{
    __shared__ float red[4 * 63 * RSTRIDE];   // 65,520 B
    const int b     = blockIdx.x / CHUNKS;
    const int chunk = blockIdx.x % CHUNKS;
    const int w     = threadIdx.x >> 6;       // wave id 0..3
    const int lane  = threadIdx.x & 63;
    const int cls[3] = { w, w + 4, w + 8 };   // this wave's classes

    // proj_idx for my 3 classes (argmax over 16 rows, first max, /G), scalarized
    int pj[3];
    #pragma unroll
    for (int k = 0; k < 3; ++k) {
        int best = 0; float bv = gci[cls[k]];
        #pragma unroll
        for (int r = 1; r < P_ * G_; ++r) {
            const float v = gci[r * C_ + cls[k]];
            if (v > bv) { bv = v; best = r; }
        }
        pj[k] = __builtin_amdgcn_readfirstlane(best >> 2);
    }
    const bool same = (pj[1] == pj[0]) && (pj[2] == pj[0]);   // wave-uniform

    const int* __restrict__ lab = labels + (size_t)b * NPIX + chunk * TILE;
    int lv[ROUNDS];
    #pragma unroll
    for (int r = 0; r < ROUNDS; ++r) lv[r] = lab[r * 64 + lane];

    float acc[63];
    #pragma unroll
    for (int i = 0; i < 63; ++i) acc[i] = 0.0f;

    if (same) {
        // FAST PATH: dense coalesced stream of the one plane covering all 3 classes
        const float4* __restrict__ pp = reinterpret_cast<const float4*>(
            act + ((size_t)(pj[0] * B_ + b) * NPIX + (size_t)chunk * TILE) * G_);
        #pragma unroll
        for (int r = 0; r < ROUNDS; ++r) {
            const float4 v = pp[r * 64 + lane];
            const int l   = lv[r];
            const int cef = ((unsigned)(l - 1) < (unsigned)C_) ? (l - 1) : 255;
            const float vv[4] = { v.x, v.y, v.z, v.w };
            float ee[4], wag[16];
            #pragma unroll
            for (int a = 0; a < 4; ++a) ee[a] = __expf(vv[a]);
            #pragma unroll
            for (int a = 0; a < 4; ++a)
                #pragma unroll
                for (int g = 0; g < 4; ++g) wag[a * 4 + g] = ee[a] * vv[g];
            #pragma unroll
            for (int k = 0; k < 3; ++k) {
                const float m = (cef == cls[k]) ? 1.0f : 0.0f;   // predicated, no branch
                acc[k * 21 + 20] += m;
                #pragma unroll
                for (int a = 0; a < 4; ++a)
                    acc[k * 21 + 16 + a] = fmaf(m, ee[a], acc[k * 21 + 16 + a]);
                #pragma unroll
                for (int i = 0; i < 16; ++i)
                    acc[k * 21 + i] = fmaf(m, wag[i], acc[k * 21 + i]);
            }
        }
    } else {
        // FALLBACK (general gci): masked gather per class (round-3 proven path)
        for (int r = 0; r < ROUNDS; ++r) {
            const int n   = chunk * TILE + r * 64 + lane;
            const int l   = lv[r];
            const int cef = ((unsigned)(l - 1) < (unsigned)C_) ? (l - 1) : 255;
            #pragma unroll
            for (int k = 0; k < 3; ++k) {
                if (cef == cls[k]) {
                    const float4 v = *reinterpret_cast<const float4*>(
                        act + (((size_t)(pj[k] * B_ + b) * NPIX) + (size_t)n) * G_);
                    const float vv[4] = { v.x, v.y, v.z, v.w };
                    #pragma unroll
                    for (int a = 0; a < 4; ++a) {
                        const float e = __expf(vv[a]);
                        acc[k * 21 + 16 + a] += e;
                        #pragma unroll
                        for (int g = 0; g < 4; ++g)
                            acc[k * 21 + a * 4 + g] = fmaf(e, vv[g], acc[k * 21 + a * 4 + g]);
                    }
                    acc[k * 21 + 20] += 1.0f;
                }
            }
        }
    }

    // block reduce: LDS transpose (conflict-free via odd row stride)
    float* base = red + w * 63 * RSTRIDE;
    #pragma unroll
    for (int i = 0; i < 63; ++i) base[i * RSTRIDE + lane] = acc[i];
    __syncthreads();
    if (lane < 63) {
        float s = 0.0f;
        #pragma unroll
        for (int j = 0; j < 64; ++j) s += base[lane * RSTRIDE + j];
        const int k = lane / 21, i = lane % 21;
        const int c = w + k * 4;
        partials[(size_t)chunk * NSLOT + ((size_t)c * B_ + b) * 21 + i] = s;
    }
}

__global__ __launch_bounds__(1024) void kld_finalize(
    const float* __restrict__ partials,  // [CHUNKS][NSLOT]
    const float* __restrict__ proto,     // [120, C]
    float*       __restrict__ out)
{
    __shared__ float s_sum[NSLOT];
    __shared__ float s_ok[C_];
    __shared__ float s_tot[128];
    __shared__ float s_den[128];
    const int t = threadIdx.x;

    if (t < C_) {   // proto_ok[c] = column sum > 0
        float s = 0.0f;
        #pragma unroll
        for (int r = 0; r < 120; ++r) s += proto[r * C_ + t];
        s_ok[t] = s;
    }

    // phase 1: sum each slot over CHUNKS (coalesced across threads per q-step)
    for (int s = t; s < NSLOT; s += 1024) {
        float a = 0.0f;
        #pragma unroll
        for (int q = 0; q < CHUNKS; ++q) a += partials[(size_t)q * NSLOT + s];
        s_sum[s] = a;
    }
    __syncthreads();

    // phase 2: one thread per (c,b) pair
    float tot = 0.0f, den = 0.0f;
    if (t < C_ * B_) {
        const int c = t / B_;
        const float* slot = s_sum + t * 21;
        const float cnt = slot[20];
        if (s_ok[c] > 0.0f && cnt >= 2.0f) {
            float S[4][4];
            #pragma unroll
            for (int a = 0; a < 4; ++a) {
                const float zinv = 1.0f / slot[16 + a];
                #pragma unroll
                for (int g = 0; g < 4; ++g)
                    S[a][g] = slot[a * 4 + g] * zinv;
            }
            #pragma unroll
            for (int j = 0; j < 4; ++j)
                #pragma unroll
                for (int k = 0; k < 4; ++k)
                    if (k > j) {
                        const float kld = 0.5f * (S[j][j] + S[k][k] - S[j][k] - S[k][j]);
                        tot += __expf(-kld);
                    }
            den = 6.0f;   // G*(G-1)/2 pairs
        }
    }

    if (t < 128) { s_tot[t] = tot; s_den[t] = den; }
    __syncthreads();
    #pragma unroll
    for (int s = 64; s >= 1; s >>= 1) {
        if (t < s) { s_tot[t] += s_tot[t + s]; s_den[t] += s_den[t + s]; }
        __syncthreads();
    }
    if (t == 0)
        out[0] = (s_den[0] > 0.0f) ? (s_tot[0] / s_den[0]) : 0.0f;
}

extern "C" void kernel_launch(void* const* d_in, const int* in_sizes, int n_in,
                              void* d_out, int out_size, void* d_ws, size_t ws_size,
                              hipStream_t stream) {
    const float* act    = (const float*)d_in[0];  // [P,B,N,G] fp32
    const int*   labels = (const int*)d_in[1];    // [B,H,W] int32
    const float* proto  = (const float*)d_in[2];  // [120, C] fp32
    const float* gci    = (const float*)d_in[3];  // [P*G, C] fp32
    float* out = (float*)d_out;
    float* ws  = (float*)d_ws;   // 516 KiB used; every element written by stage1

    kld_stage1<<<NBLK, 256, 0, stream>>>(act, labels, gci, ws);
    kld_finalize<<<1, 1024, 0, stream>>>(ws, proto, out);
}